// Round 4
// baseline (565.772 us; speedup 1.0000x reference)
//
#include <hip/hip_runtime.h>
#include <hip/hip_fp16.h>

// Problem constants: C=64, S=2048, H=512; rows = C*S = 131072
#define HDIM 512

typedef __fp16 fp16x2 __attribute__((ext_vector_type(2)));
typedef _Float16 h8 __attribute__((ext_vector_type(8)));
typedef __attribute__((ext_vector_type(4))) float floatx4;

// ---------------------------------------------------------------------------
// Kernel 1: W fp32 -> fp16 (RTE)
// ---------------------------------------------------------------------------
__global__ __launch_bounds__(256) void prep_w_kernel(
    const float* __restrict__ W, _Float16* __restrict__ wf) {
  int i = (blockIdx.x * 256 + threadIdx.x) * 4;
  float4 f = *(const float4*)(W + i);
  wf[i + 0] = (_Float16)f.x;
  wf[i + 1] = (_Float16)f.y;
  wf[i + 2] = (_Float16)f.z;
  wf[i + 3] = (_Float16)f.w;
}

// ---------------------------------------------------------------------------
// Kernel 2: GEMM, software-pipelined K-loop:
//   - W double-buffered in LDS; dma(kt+1) + x-reg loads issued DURING compute
//     so barrier drains wait on already-landed loads (removes the per-kt stall)
// ---------------------------------------------------------------------------
__global__ __launch_bounds__(256) void gemm_kernel(
    const float* __restrict__ x, const _Float16* __restrict__ wf,
    const float* __restrict__ bias, __half* __restrict__ y,
    float* __restrict__ sq) {
  __shared__ _Float16 xs[128 * 64];
  __shared__ _Float16 wsm[2][128 * 64];

  const int tid = threadIdx.x;
  const int lane = tid & 63;
  const int widx = tid >> 6;
  const int wave_m = widx >> 1, wave_n = widx & 1;
  const int lrow = lane & 15, quad = lane >> 4, l7 = lane & 7;

  const int bid = blockIdx.x;
  const int m_blk = ((bid >> 5) << 3) + (bid & 7);
  const int n_blk = (bid >> 3) & 3;
  const int row0 = m_blk * 128;
  const int col0 = n_blk * 128;

  floatx4 acc[4][4];
#pragma unroll
  for (int i = 0; i < 4; ++i)
#pragma unroll
    for (int j = 0; j < 4; ++j) acc[i][j] = (floatx4){0.f, 0.f, 0.f, 0.f};

  const int xm = tid >> 3;
  const int xkg = tid & 7;
  const int wn_sub = lane >> 3;
  const int wphys = lane & 7;

  float4 xr[4][2];
  const float* xbase = x + (size_t)row0 * HDIM + xkg * 8;
  // prologue: x(0) into regs
#pragma unroll
  for (int p = 0; p < 4; ++p) {
    const float* gp = xbase + (size_t)(p * 32 + xm) * HDIM;
    xr[p][0] = *(const float4*)gp;
    xr[p][1] = *(const float4*)(gp + 4);
  }
  // prologue: W dma(0) -> wsm[0]
#pragma unroll
  for (int q = 0; q < 4; ++q) {
    int i = widx * 4 + q;
    int n_loc = 8 * i + wn_sub;
    int kg_l = wphys ^ (n_loc & 7);
    size_t goff = (size_t)(col0 + n_loc) * HDIM + kg_l * 8;
    __builtin_amdgcn_global_load_lds(
        (const __attribute__((address_space(1))) void*)(wf + goff),
        (__attribute__((address_space(3))) void*)&wsm[0][i * 512], 16, 0, 0);
  }

  for (int kt = 0; kt < 8; ++kt) {
    __syncthreads();  // drains x(kt) regs + W dma(kt): issued one phase ago
    // ---- stage x regs -> LDS (pkrtz, swizzled) ----
#pragma unroll
    for (int p = 0; p < 4; ++p) {
      int m = p * 32 + xm;
      union { h8 v8; fp16x2 v2[4]; } u;
      u.v2[0] = __builtin_amdgcn_cvt_pkrtz(xr[p][0].x, xr[p][0].y);
      u.v2[1] = __builtin_amdgcn_cvt_pkrtz(xr[p][0].z, xr[p][0].w);
      u.v2[2] = __builtin_amdgcn_cvt_pkrtz(xr[p][1].x, xr[p][1].y);
      u.v2[3] = __builtin_amdgcn_cvt_pkrtz(xr[p][1].z, xr[p][1].w);
      int phys = xkg ^ (m & 7);
      *(h8*)&xs[m * 64 + phys * 8] = u.v8;
    }
    __syncthreads();  // only LDS writes outstanding: cheap drain
    // ---- issue next-kt loads, overlapped with MFMA compute ----
    if (kt < 7) {
      const int k1 = (kt + 1) * 64;
      _Float16* wdst = &wsm[(kt + 1) & 1][0];
#pragma unroll
      for (int q = 0; q < 4; ++q) {
        int i = widx * 4 + q;
        int n_loc = 8 * i + wn_sub;
        int kg_l = wphys ^ (n_loc & 7);
        size_t goff = (size_t)(col0 + n_loc) * HDIM + k1 + kg_l * 8;
        __builtin_amdgcn_global_load_lds(
            (const __attribute__((address_space(1))) void*)(wf + goff),
            (__attribute__((address_space(3))) void*)&wdst[i * 512], 16, 0, 0);
      }
#pragma unroll
      for (int p = 0; p < 4; ++p) {
        const float* gp = xbase + (size_t)(p * 32 + xm) * HDIM + k1;
        xr[p][0] = *(const float4*)gp;
        xr[p][1] = *(const float4*)(gp + 4);
      }
    }
    // ---- compute ----
    const _Float16* wcur = &wsm[kt & 1][0];
#pragma unroll
    for (int ks = 0; ks < 2; ++ks) {
      int physA = (ks * 4 + quad) ^ l7;
      h8 a[4], bh[4];
#pragma unroll
      for (int mt = 0; mt < 4; ++mt) {
        int r = wave_m * 64 + mt * 16 + lrow;
        a[mt] = *(const h8*)&xs[r * 64 + physA * 8];
      }
#pragma unroll
      for (int nt = 0; nt < 4; ++nt) {
        int c = wave_n * 64 + nt * 16 + lrow;
        bh[nt] = *(const h8*)&wcur[c * 64 + physA * 8];
      }
#pragma unroll
      for (int mt = 0; mt < 4; ++mt)
#pragma unroll
        for (int nt = 0; nt < 4; ++nt)
          acc[mt][nt] = __builtin_amdgcn_mfma_f32_16x16x32_f16(
              a[mt], bh[nt], acc[mt][nt], 0, 0, 0);
    }
  }

  // ---- epilogue ----
  int colg[4];
  float bias_v[4];
#pragma unroll
  for (int nt = 0; nt < 4; ++nt) {
    colg[nt] = col0 + wave_n * 64 + nt * 16 + lrow;
    bias_v[nt] = bias[colg[nt]];
  }
#pragma unroll
  for (int mt = 0; mt < 4; ++mt) {
#pragma unroll
    for (int r = 0; r < 4; ++r) {
      int rowg = row0 + wave_m * 64 + mt * 16 + quad * 4 + r;
      float s = 0.f;
#pragma unroll
      for (int nt = 0; nt < 4; ++nt) {
        float yv = acc[mt][nt][r] + bias_v[nt];
        s += yv * yv;
        y[(size_t)rowg * HDIM + colg[nt]] = __float2half(yv);
      }
      s += __shfl_xor(s, 1, 64);
      s += __shfl_xor(s, 2, 64);
      s += __shfl_xor(s, 4, 64);
      s += __shfl_xor(s, 8, 64);
      if (lrow == 0) atomicAdd(&sq[rowg], s);
    }
  }
}

// ---------------------------------------------------------------------------
// Kernel 3 (fused routing pass), ILP-restructured:
//   8-row register-resident chunks; batched butterfly over 8 dots; exp +
//   u-accumulate with y still in registers; intra-block LDS reduce of u/den.
// ---------------------------------------------------------------------------
__global__ __launch_bounds__(256) void kbv_kernel(
    const __half* __restrict__ y, const float* __restrict__ sqbuf,
    float* __restrict__ b, const float* __restrict__ c_buf,
    float* __restrict__ u_part, float* __restrict__ den_part) {
  const int w = threadIdx.x >> 6;
  const int lane = threadIdx.x & 63;
  const int wave_g = blockIdx.x * 4 + w;
  const int cap = wave_g >> 6;   // 16 blocks (64 waves) per capsule
  const int chunk = wave_g & 63;
  const int r0 = cap * 2048 + chunk * 32;

  float c8[8];
  {
    const float4* cp = (const float4*)(c_buf + cap * HDIM + lane * 8);
    float4 ca = cp[0], cb = cp[1];
    c8[0] = ca.x; c8[1] = ca.y; c8[2] = ca.z; c8[3] = ca.w;
    c8[4] = cb.x; c8[5] = cb.y; c8[6] = cb.z; c8[7] = cb.w;
  }
  float u8[8] = {0, 0, 0, 0, 0, 0, 0, 0};
  float den = 0.f;

  union U { int4 v; __half hh[8]; };
  U cur[8], nxt[8];
  const __half* yb = y + (size_t)r0 * HDIM + lane * 8;
#pragma unroll
  for (int j = 0; j < 8; ++j) cur[j].v = *(const int4*)(yb + (size_t)j * HDIM);

#pragma unroll
  for (int g = 0; g < 4; ++g) {
    const int rg = r0 + g * 8;
    if (g < 3) {
#pragma unroll
      for (int j = 0; j < 8; ++j)
        nxt[j].v = *(const int4*)(yb + (size_t)(g * 8 + 8 + j) * HDIM);
    }
    float sc[8], bv[8];
#pragma unroll
    for (int j = 0; j < 8; ++j) {
      float s = sqbuf[rg + j];
      sc[j] = s / ((1.f + s) * sqrtf(s + 1e-7f));
      bv[j] = b[rg + j];
    }
    float dot[8];
#pragma unroll
    for (int j = 0; j < 8; ++j) {
      float d = 0.f;
#pragma unroll
      for (int k = 0; k < 8; ++k) d += __half2float(cur[j].hh[k]) * c8[k];
      dot[j] = d;
    }
    // batched butterfly: 8 independent chains pipeline through the shuffles
#pragma unroll
    for (int s = 1; s < 64; s <<= 1) {
#pragma unroll
      for (int j = 0; j < 8; ++j) dot[j] += __shfl_xor(dot[j], s, 64);
    }
#pragma unroll
    for (int j = 0; j < 8; ++j) {
      float bn = bv[j] + sc[j] * dot[j];
      if (lane == 0) b[rg + j] = bn;
      float wj = __expf(bn);   // |b| <= ~1e-3: no max-subtraction needed
      den += wj;
      float wsc = wj * sc[j];
#pragma unroll
      for (int k = 0; k < 8; ++k) u8[k] += wsc * __half2float(cur[j].hh[k]);
    }
#pragma unroll
    for (int j = 0; j < 8; ++j) cur[j] = nxt[j];
  }

  // intra-block reduction: 4 waves -> one partial per block
  __shared__ float lred[4][512];
  __shared__ float ldn[4];
#pragma unroll
  for (int k = 0; k < 8; ++k) lred[w][lane * 8 + k] = u8[k];
  if (lane == 0) ldn[w] = den;
  __syncthreads();
  const int t = threadIdx.x;
  const int blkc = blockIdx.x & 15;
#pragma unroll
  for (int hh = 0; hh < 2; ++hh) {
    int h = hh * 256 + t;
    float v = lred[0][h] + lred[1][h] + lred[2][h] + lred[3][h];
    u_part[((size_t)cap * 16 + blkc) * HDIM + h] = v;
  }
  if (t == 0)
    den_part[cap * 16 + blkc] = ldn[0] + ldn[1] + ldn[2] + ldn[3];
}

// ---------------------------------------------------------------------------
// Kernel 4: per capsule: v = (sum_chunk u_part)/(sum den_part); c = squash(v)
// ---------------------------------------------------------------------------
__global__ __launch_bounds__(512) void kcsq_kernel(
    const float* __restrict__ u_part, const float* __restrict__ den_part,
    float* __restrict__ out) {
  const int cap = blockIdx.x;
  const int t = threadIdx.x;
  __shared__ float red[512];
  __shared__ float sden;

  if (t < 16) red[t] = den_part[cap * 16 + t];
  __syncthreads();
  if (t == 0) {
    float s = 0.f;
#pragma unroll
    for (int i = 0; i < 16; ++i) s += red[i];
    sden = s;
  }
  __syncthreads();
  const float den = sden;

  float v = 0.f;
  const float* up = u_part + (size_t)cap * 16 * HDIM + t;
#pragma unroll
  for (int ch = 0; ch < 16; ++ch) v += up[ch * HDIM];
  v /= den;

  red[t] = v * v;
  __syncthreads();
  for (int s = 256; s > 0; s >>= 1) {
    if (t < s) red[t] += red[t + s];
    __syncthreads();
  }
  const float sqv = red[0];
  const float scv = sqv / ((1.f + sqv) * sqrtf(sqv + 1e-7f));
  out[cap * HDIM + t] = v * scv;
}

// ---------------------------------------------------------------------------
extern "C" void kernel_launch(void* const* d_in, const int* in_sizes, int n_in,
                              void* d_out, int out_size, void* d_ws,
                              size_t ws_size, hipStream_t stream) {
  const float* x = (const float*)d_in[0];     // [131072,512]
  const float* W = (const float*)d_in[1];     // [512,512]
  const float* bias = (const float*)d_in[2];  // [512]
  float* out = (float*)d_out;                 // [64,512]
  char* ws = (char*)d_ws;

  // workspace layout (~138 MB)
  __half* y = (__half*)ws;                               // 134217728 B
  float* sq = (float*)(ws + (size_t)134217728);          // 131072 f
  float* b = sq + 131072;                                // 131072 f
  float* c_buf = b + 131072;                             // 32768 f
  _Float16* wf = (_Float16*)(c_buf + 32768);             // 262144 h
  float* u_part = (float*)(wf + 262144);                 // 64*16*512 f
  float* den_part = u_part + (size_t)64 * 16 * 512;      // 1024 f

  // zero sq, b, c_buf (contiguous)
  (void)hipMemsetAsync(sq, 0,
                       (size_t)(131072 + 131072 + 32768) * sizeof(float),
                       stream);

  prep_w_kernel<<<256, 256, 0, stream>>>(W, wf);
  gemm_kernel<<<4096, 256, 0, stream>>>(x, wf, bias, y, sq);

  for (int it = 0; it < 3; ++it) {
    kbv_kernel<<<1024, 256, 0, stream>>>(y, sq, b, c_buf, u_part, den_part);
    kcsq_kernel<<<64, 512, 0, stream>>>(u_part, den_part,
                                        (it == 2) ? out : c_buf);
  }
}

// Round 5
// 535.940 us; speedup vs baseline: 1.0557x; 1.0557x over previous
//
#include <hip/hip_runtime.h>
#include <hip/hip_fp16.h>

// Problem constants: C=64, S=2048, H=512; rows = C*S = 131072
#define HDIM 512

typedef __fp16 fp16x2 __attribute__((ext_vector_type(2)));
typedef _Float16 h8 __attribute__((ext_vector_type(8)));
typedef __attribute__((ext_vector_type(4))) float floatx4;

// raw barrier: LDS-visibility only, no vmem drain (unlike __syncthreads)
__device__ __forceinline__ void lds_barrier() {
  asm volatile("s_waitcnt lgkmcnt(0)\n\ts_barrier" ::: "memory");
}
__device__ __forceinline__ void issue_fence() {  // pin vm-issue order
  asm volatile("" ::: "memory");
}

// ---------------------------------------------------------------------------
// Kernel 1: W fp32 -> fp16 (RTE)
// ---------------------------------------------------------------------------
__global__ __launch_bounds__(256) void prep_w_kernel(
    const float* __restrict__ W, _Float16* __restrict__ wf) {
  int i = (blockIdx.x * 256 + threadIdx.x) * 4;
  float4 f = *(const float4*)(W + i);
  wf[i + 0] = (_Float16)f.x;
  wf[i + 1] = (_Float16)f.y;
  wf[i + 2] = (_Float16)f.z;
  wf[i + 3] = (_Float16)f.w;
}

// ---------------------------------------------------------------------------
// Kernel 2: GEMM with non-draining barriers + distance-2 x prefetch +
// hand-counted vmcnt waits for the W dma + per-block K-rotation (anti-convoy).
// ---------------------------------------------------------------------------
__device__ __forceinline__ void issue_w_dma(const _Float16* wf, _Float16* dst,
                                            int col0, int kt, int widx,
                                            int wn_sub, int wphys) {
#pragma unroll
  for (int q = 0; q < 4; ++q) {
    int i = widx * 4 + q;            // instr id 0..15, 8 rows each
    int n_loc = 8 * i + wn_sub;
    int kg_l = wphys ^ (n_loc & 7);  // source-side XOR swizzle
    size_t goff = (size_t)(col0 + n_loc) * HDIM + kt * 64 + kg_l * 8;
    __builtin_amdgcn_global_load_lds(
        (const __attribute__((address_space(1))) void*)(wf + goff),
        (__attribute__((address_space(3))) void*)(dst + i * 512), 16, 0, 0);
  }
}

__global__ __launch_bounds__(256) void gemm_kernel(
    const float* __restrict__ x, const _Float16* __restrict__ wf,
    const float* __restrict__ bias, __half* __restrict__ y,
    float* __restrict__ sq) {
  __shared__ _Float16 xs[128 * 64];
  __shared__ _Float16 wsm[2][128 * 64];

  const int tid = threadIdx.x;
  const int lane = tid & 63;
  const int widx = tid >> 6;
  const int wave_m = widx >> 1, wave_n = widx & 1;
  const int lrow = lane & 15, quad = lane >> 4, l7 = lane & 7;

  const int bid = blockIdx.x;
  const int m_blk = ((bid >> 5) << 3) + (bid & 7);
  const int n_blk = (bid >> 3) & 3;
  const int row0 = m_blk * 128;
  const int col0 = n_blk * 128;
  const int kt0 = bid & 7;  // K-rotation: x-sharing blocks (same bid&7) align

  floatx4 acc[4][4];
#pragma unroll
  for (int i = 0; i < 4; ++i)
#pragma unroll
    for (int j = 0; j < 4; ++j) acc[i][j] = (floatx4){0.f, 0.f, 0.f, 0.f};

  const int xm = tid >> 3;
  const int xkg = tid & 7;
  const int wn_sub = lane >> 3;
  const int wphys = lane & 7;

  const float* xbase = x + (size_t)row0 * HDIM + xkg * 8;
  float4 xr[2][4][2];

  // prologue: dma_0 ; fence ; x_0 ; x_1   (FIFO: [dma_0, x_0, x_1])
  issue_w_dma(wf, &wsm[0][0], col0, kt0, widx, wn_sub, wphys);
  issue_fence();
#pragma unroll
  for (int p = 0; p < 4; ++p) {
    const float* gp = xbase + (size_t)(p * 32 + xm) * HDIM + kt0 * 64;
    xr[0][p][0] = *(const float4*)gp;
    xr[0][p][1] = *(const float4*)(gp + 4);
  }
  issue_fence();
#pragma unroll
  for (int p = 0; p < 4; ++p) {
    const float* gp =
        xbase + (size_t)(p * 32 + xm) * HDIM + ((kt0 + 1) & 7) * 64;
    xr[1][p][0] = *(const float4*)gp;
    xr[1][p][1] = *(const float4*)(gp + 4);
  }

#pragma unroll
  for (int i = 0; i < 8; ++i) {
    lds_barrier();  // B1: xs(prev) fully read by all waves; no vmem drain
    // ---- stage x_i: regs -> pkrtz -> xs (compiler waits exactly x_i here) --
#pragma unroll
    for (int p = 0; p < 4; ++p) {
      int m = p * 32 + xm;
      union { h8 v8; fp16x2 v2[4]; } u;
      u.v2[0] = __builtin_amdgcn_cvt_pkrtz(xr[i & 1][p][0].x, xr[i & 1][p][0].y);
      u.v2[1] = __builtin_amdgcn_cvt_pkrtz(xr[i & 1][p][0].z, xr[i & 1][p][0].w);
      u.v2[2] = __builtin_amdgcn_cvt_pkrtz(xr[i & 1][p][1].x, xr[i & 1][p][1].y);
      u.v2[3] = __builtin_amdgcn_cvt_pkrtz(xr[i & 1][p][1].z, xr[i & 1][p][1].w);
      int phys = xkg ^ (m & 7);
      *(h8*)&xs[m * 64 + phys * 8] = u.v8;
    }
    lds_barrier();  // B2: xs(i) visible; no vmem drain
    // ---- issue next loads: [dma_{i+1}] fence [x_{i+2}] ----
    if (i < 7)
      issue_w_dma(wf, &wsm[(i + 1) & 1][0], col0, (kt0 + i + 1) & 7, widx,
                  wn_sub, wphys);
    issue_fence();
    if (i < 6) {
      const int ktn = (kt0 + i + 2) & 7;
#pragma unroll
      for (int p = 0; p < 4; ++p) {
        const float* gp = xbase + (size_t)(p * 32 + xm) * HDIM + ktn * 64;
        xr[i & 1][p][0] = *(const float4*)gp;
        xr[i & 1][p][1] = *(const float4*)(gp + 4);
      }
    }
    // ---- drain dma_i before reading wsm[i&1] ----
    // queue: i=0: dma_0 already drained by stage(0)'s x_0 wait.
    // i=1..5: [dma_i 4, x_{i+1} 8, dma_{i+1} 4, x_{i+2} 8] -> vmcnt(20)
    // i=6:    [dma_6 4, x_7 8, dma_7 4]                    -> vmcnt(12)
    // i=7:    [dma_7 4]                                    -> vmcnt(0)
    if (i >= 1 && i <= 5) asm volatile("s_waitcnt vmcnt(20)" ::: "memory");
    if (i == 6) asm volatile("s_waitcnt vmcnt(12)" ::: "memory");
    if (i == 7) asm volatile("s_waitcnt vmcnt(0)" ::: "memory");
    // ---- compute ----
    const _Float16* wcur = &wsm[i & 1][0];
#pragma unroll
    for (int ks = 0; ks < 2; ++ks) {
      int physA = (ks * 4 + quad) ^ l7;
      h8 a[4], bh[4];
#pragma unroll
      for (int mt = 0; mt < 4; ++mt) {
        int r = wave_m * 64 + mt * 16 + lrow;
        a[mt] = *(const h8*)&xs[r * 64 + physA * 8];
      }
#pragma unroll
      for (int nt = 0; nt < 4; ++nt) {
        int c = wave_n * 64 + nt * 16 + lrow;
        bh[nt] = *(const h8*)&wcur[c * 64 + physA * 8];
      }
#pragma unroll
      for (int mt = 0; mt < 4; ++mt)
#pragma unroll
        for (int nt = 0; nt < 4; ++nt)
          acc[mt][nt] = __builtin_amdgcn_mfma_f32_16x16x32_f16(
              a[mt], bh[nt], acc[mt][nt], 0, 0, 0);
    }
  }

  // ---- epilogue ----
  int colg[4];
  float bias_v[4];
#pragma unroll
  for (int nt = 0; nt < 4; ++nt) {
    colg[nt] = col0 + wave_n * 64 + nt * 16 + lrow;
    bias_v[nt] = bias[colg[nt]];
  }
#pragma unroll
  for (int mt = 0; mt < 4; ++mt) {
#pragma unroll
    for (int r = 0; r < 4; ++r) {
      int rowg = row0 + wave_m * 64 + mt * 16 + quad * 4 + r;
      float s = 0.f;
#pragma unroll
      for (int nt = 0; nt < 4; ++nt) {
        float yv = acc[mt][nt][r] + bias_v[nt];
        s += yv * yv;
        y[(size_t)rowg * HDIM + colg[nt]] = __float2half(yv);
      }
      s += __shfl_xor(s, 1, 64);
      s += __shfl_xor(s, 2, 64);
      s += __shfl_xor(s, 4, 64);
      s += __shfl_xor(s, 8, 64);
      if (lrow == 0) atomicAdd(&sq[rowg], s);
    }
  }
}

// ---------------------------------------------------------------------------
// Kernel 3 (fused routing pass): 4-row groups (low VGPR, no spill) +
// intra-block LDS reduction (16 partials per capsule).
// ---------------------------------------------------------------------------
__global__ __launch_bounds__(256) void kbv_kernel(
    const __half* __restrict__ y, const float* __restrict__ sqbuf,
    float* __restrict__ b, const float* __restrict__ c_buf,
    float* __restrict__ u_part, float* __restrict__ den_part) {
  const int w = threadIdx.x >> 6;
  const int lane = threadIdx.x & 63;
  const int wave_g = blockIdx.x * 4 + w;
  const int cap = wave_g >> 6;
  const int chunk = wave_g & 63;
  const int r0 = cap * 2048 + chunk * 32;

  float c8[8];
  {
    const float4* cp = (const float4*)(c_buf + cap * HDIM + lane * 8);
    float4 ca = cp[0], cb = cp[1];
    c8[0] = ca.x; c8[1] = ca.y; c8[2] = ca.z; c8[3] = ca.w;
    c8[4] = cb.x; c8[5] = cb.y; c8[6] = cb.z; c8[7] = cb.w;
  }
  float u8[8] = {0, 0, 0, 0, 0, 0, 0, 0};
  float den = 0.f;

  union U { int4 v; __half hh[8]; };
  U cur[4], nxt[4];
  const __half* yb = y + (size_t)r0 * HDIM + lane * 8;
#pragma unroll
  for (int j = 0; j < 4; ++j) cur[j].v = *(const int4*)(yb + (size_t)j * HDIM);

  for (int g = 0; g < 8; ++g) {
    const int rg = r0 + g * 4;
    if (g < 7) {
#pragma unroll
      for (int j = 0; j < 4; ++j)
        nxt[j].v = *(const int4*)(yb + (size_t)(g * 4 + 4 + j) * HDIM);
    }
    float sc[4], bv[4];
#pragma unroll
    for (int j = 0; j < 4; ++j) {
      float s = sqbuf[rg + j];
      sc[j] = s / ((1.f + s) * sqrtf(s + 1e-7f));
      bv[j] = b[rg + j];
    }
    float dot[4];
#pragma unroll
    for (int j = 0; j < 4; ++j) {
      float d = 0.f;
#pragma unroll
      for (int k = 0; k < 8; ++k) d += __half2float(cur[j].hh[k]) * c8[k];
      dot[j] = d;
    }
#pragma unroll
    for (int s = 1; s < 64; s <<= 1) {
#pragma unroll
      for (int j = 0; j < 4; ++j) dot[j] += __shfl_xor(dot[j], s, 64);
    }
#pragma unroll
    for (int j = 0; j < 4; ++j) {
      float bn = bv[j] + sc[j] * dot[j];
      if (lane == 0) b[rg + j] = bn;
      float wj = __expf(bn);  // |b| <= ~1e-3: no max-subtraction needed
      den += wj;
      float wsc = wj * sc[j];
#pragma unroll
      for (int k = 0; k < 8; ++k) u8[k] += wsc * __half2float(cur[j].hh[k]);
    }
#pragma unroll
    for (int j = 0; j < 4; ++j) cur[j] = nxt[j];
  }

  // intra-block reduction: 4 waves -> one partial per block
  __shared__ float lred[4][512];
  __shared__ float ldn[4];
#pragma unroll
  for (int k = 0; k < 8; ++k) lred[w][lane * 8 + k] = u8[k];
  if (lane == 0) ldn[w] = den;
  __syncthreads();
  const int t = threadIdx.x;
  const int blkc = blockIdx.x & 15;
#pragma unroll
  for (int hh = 0; hh < 2; ++hh) {
    int h = hh * 256 + t;
    float v = lred[0][h] + lred[1][h] + lred[2][h] + lred[3][h];
    u_part[((size_t)cap * 16 + blkc) * HDIM + h] = v;
  }
  if (t == 0)
    den_part[cap * 16 + blkc] = ldn[0] + ldn[1] + ldn[2] + ldn[3];
}

// ---------------------------------------------------------------------------
// Kernel 4: per capsule: v = (sum_chunk u_part)/(sum den_part); c = squash(v)
// ---------------------------------------------------------------------------
__global__ __launch_bounds__(512) void kcsq_kernel(
    const float* __restrict__ u_part, const float* __restrict__ den_part,
    float* __restrict__ out) {
  const int cap = blockIdx.x;
  const int t = threadIdx.x;
  __shared__ float red[512];
  __shared__ float sden;

  if (t < 16) red[t] = den_part[cap * 16 + t];
  __syncthreads();
  if (t == 0) {
    float s = 0.f;
#pragma unroll
    for (int i = 0; i < 16; ++i) s += red[i];
    sden = s;
  }
  __syncthreads();
  const float den = sden;

  float v = 0.f;
  const float* up = u_part + (size_t)cap * 16 * HDIM + t;
#pragma unroll
  for (int ch = 0; ch < 16; ++ch) v += up[ch * HDIM];
  v /= den;

  red[t] = v * v;
  __syncthreads();
  for (int s = 256; s > 0; s >>= 1) {
    if (t < s) red[t] += red[t + s];
    __syncthreads();
  }
  const float sqv = red[0];
  const float scv = sqv / ((1.f + sqv) * sqrtf(sqv + 1e-7f));
  out[cap * HDIM + t] = v * scv;
}

// ---------------------------------------------------------------------------
extern "C" void kernel_launch(void* const* d_in, const int* in_sizes, int n_in,
                              void* d_out, int out_size, void* d_ws,
                              size_t ws_size, hipStream_t stream) {
  const float* x = (const float*)d_in[0];     // [131072,512]
  const float* W = (const float*)d_in[1];     // [512,512]
  const float* bias = (const float*)d_in[2];  // [512]
  float* out = (float*)d_out;                 // [64,512]
  char* ws = (char*)d_ws;

  __half* y = (__half*)ws;                               // 134217728 B
  float* sq = (float*)(ws + (size_t)134217728);          // 131072 f
  float* b = sq + 131072;                                // 131072 f
  float* c_buf = b + 131072;                             // 32768 f
  _Float16* wf = (_Float16*)(c_buf + 32768);             // 262144 h
  float* u_part = (float*)(wf + 262144);                 // 64*16*512 f
  float* den_part = u_part + (size_t)64 * 16 * 512;      // 1024 f

  (void)hipMemsetAsync(sq, 0,
                       (size_t)(131072 + 131072 + 32768) * sizeof(float),
                       stream);

  prep_w_kernel<<<256, 256, 0, stream>>>(W, wf);
  gemm_kernel<<<4096, 256, 0, stream>>>(x, wf, bias, y, sq);

  for (int it = 0; it < 3; ++it) {
    kbv_kernel<<<1024, 256, 0, stream>>>(y, sq, b, c_buf, u_part, den_part);
    kcsq_kernel<<<64, 512, 0, stream>>>(u_part, den_part,
                                        (it == 2) ? out : c_buf);
  }
}